// Round 2
// baseline (237.002 us; speedup 1.0000x reference)
//
#include <hip/hip_runtime.h>
#include <hip/hip_bf16.h>

// RGCN encoder, MI355X. Algebraic identities (verified against reference):
//  - only layer-2 weights/biases are live (reference recomputes from
//    `embeddings` each layer and overwrites `output`)
//  - messages scatter to their own source node (sources == dests), so
//    out[n] = sum_r (c[n][r]/cnt[n]) * (emb[n] @ W2[r] + b2[r]), r in [0,18)
// Dtypes (round-1 fix): floats are FP32 in/out (NaN forensics: fp32 read as
// bf16 pairs injects NaN bit patterns from mantissa halves). Ints are int32.
// Compute path: fp32 -> bf16 (RNE) -> 16x16x32 bf16 MFMA -> fp32 accum/out.

typedef float  floatx4 __attribute__((ext_vector_type(4)));
typedef short  shortx8 __attribute__((ext_vector_type(8)));

#define MFMA_BF16(A, B, C) __builtin_amdgcn_mfma_f32_16x16x32_bf16((A), (B), (C), 0, 0, 0)

static __device__ __forceinline__ ushort f32_to_bf16_rne(float f) {
    union { float f; unsigned u; } v; v.f = f;
    unsigned r = v.u + 0x7fffu + ((v.u >> 16) & 1u);
    return (ushort)(r >> 16);
}

// ---- prep: wt[r][o][k] = bf16(W2[r][k][o]), bias_t[o][rr] = bf16(b2[rr][o])
__global__ void rgcn_prep(const float* __restrict__ w2,   // fp32 [18][64][64]
                          const float* __restrict__ b2,   // fp32 [18][64]
                          ushort* __restrict__ wt,        // bf16 [18][64][64] (r,o,k)
                          ushort* __restrict__ bias_t) {  // bf16 [64][32]
    int i = blockIdx.x * 256 + threadIdx.x;
    const int WELEMS = 18 * 64 * 64;
    if (i < WELEMS) {
        int r = i >> 12;          // /4096
        int o = (i >> 6) & 63;
        int k = i & 63;
        wt[i] = f32_to_bf16_rne(w2[(r << 12) + (k << 6) + o]);
    } else {
        int j = i - WELEMS;
        if (j < 64 * 32) {
            int o = j >> 5;
            int rr = j & 31;
            bias_t[j] = (rr < 18) ? f32_to_bf16_rne(b2[rr * 64 + o]) : (ushort)0;
        }
    }
}

// ---- edge incidence counts: c[n][r] for r in [0,18)
__global__ void rgcn_count(const int* __restrict__ ei,  // [2][E] int32
                           const int* __restrict__ et,  // [E]    int32
                           int* __restrict__ cnts,      // [N][18]
                           int E, int N) {
    int e = blockIdx.x * 256 + threadIdx.x;
    if (e < E) {
        int r = et[e];
        int i0 = ei[e];
        int i1 = ei[E + e];
        if ((unsigned)r < 9u) {
            if ((unsigned)i0 < (unsigned)N) atomicAdd(&cnts[i0 * 18 + r], 1);
            if ((unsigned)i1 < (unsigned)N) atomicAdd(&cnts[i1 * 18 + 9 + r], 1);
        }
    }
}

// ---- fused main kernel: 128 nodes/block, 4 waves, each wave 32 rows x 64 cols
__global__ __launch_bounds__(256) void rgcn_main(
    const float*  __restrict__ emb,     // fp32 [N][64]
    const int*    __restrict__ cnts,    // [N][18]
    const ushort* __restrict__ wt,      // bf16 [18][64][64]  (r, o, k)
    const ushort* __restrict__ bias_t,  // bf16 [64][32]      (o, rr)
    float*        __restrict__ out,     // fp32 [N][64]
    int N)
{
    __shared__ float  wf[128][19];   // fp32 w-hat, padded stride
    __shared__ ushort wb[128][32];   // bf16 w-hat, k-padded to 32 for bias MFMA

    const int t  = threadIdx.x;
    const int nb = blockIdx.x * 128;

    // phase 1: per-node normalized relation weights
    if (t < 128) {
        int n = nb + t;
        int c[18];
        int cnt = 0;
        if (n < N) {
            #pragma unroll
            for (int r = 0; r < 18; r++) { c[r] = cnts[n * 18 + r]; cnt += c[r]; }
        } else {
            #pragma unroll
            for (int r = 0; r < 18; r++) c[r] = 0;
        }
        float inv = (cnt > 0) ? (1.0f / (float)cnt) : 0.0f;
        #pragma unroll
        for (int r = 0; r < 18; r++) {
            float w = (float)c[r] * inv;
            wf[t][r] = w;
            wb[t][r] = f32_to_bf16_rne(w);
        }
        #pragma unroll
        for (int r = 18; r < 32; r++) wb[t][r] = 0;
    }
    __syncthreads();

    const int wave = t >> 6;
    const int lane = t & 63;
    const int m    = lane & 15;   // A row / B col / D col within 16-tile
    const int q    = lane >> 4;   // quad: k-group for A/B, row-group for D

    // phase 2: A fragments (embeddings fp32 -> bf16), constant across r.
    // A-frag layout: lane holds A[m][k = q*8 + j], j=0..7.
    shortx8 afrag[2][2];
    #pragma unroll
    for (int mt = 0; mt < 2; mt++) {
        int row = wave * 32 + mt * 16 + m;
        int n = nb + row;
        if (n >= N) n = N - 1;               // clamp; contribution zeroed by w-hat=0
        const float* rp = emb + (size_t)n * 64 + q * 8;
        #pragma unroll
        for (int kh = 0; kh < 2; kh++) {
            floatx4 lo = *(const floatx4*)(rp + kh * 32);
            floatx4 hi = *(const floatx4*)(rp + kh * 32 + 4);
            shortx8 f;
            #pragma unroll
            for (int j = 0; j < 4; j++) {
                f[j]     = (short)f32_to_bf16_rne(lo[j]);
                f[j + 4] = (short)f32_to_bf16_rne(hi[j]);
            }
            afrag[mt][kh] = f;
        }
    }

    floatx4 acc[2][4];
    #pragma unroll
    for (int mt = 0; mt < 2; mt++)
        #pragma unroll
        for (int nt = 0; nt < 4; nt++)
            acc[mt][nt] = (floatx4){0.f, 0.f, 0.f, 0.f};

    // phase 3: per-relation partial GEMM, scaled into persistent accumulators
    for (int r = 0; r < 18; r++) {
        shortx8 bfrag[4][2];
        #pragma unroll
        for (int nt = 0; nt < 4; nt++)
            #pragma unroll
            for (int kh = 0; kh < 2; kh++)
                bfrag[nt][kh] = *(const shortx8*)(wt + r * 4096 + (nt * 16 + m) * 64 + kh * 32 + q * 8);

        float sw[2][4];
        #pragma unroll
        for (int mt = 0; mt < 2; mt++)
            #pragma unroll
            for (int i = 0; i < 4; i++)
                sw[mt][i] = wf[wave * 32 + mt * 16 + q * 4 + i][r];   // LDS broadcast

        #pragma unroll
        for (int mt = 0; mt < 2; mt++) {
            #pragma unroll
            for (int nt = 0; nt < 4; nt++) {
                floatx4 tmp = (floatx4){0.f, 0.f, 0.f, 0.f};
                tmp = MFMA_BF16(afrag[mt][0], bfrag[nt][0], tmp);
                tmp = MFMA_BF16(afrag[mt][1], bfrag[nt][1], tmp);
                #pragma unroll
                for (int i = 0; i < 4; i++)
                    acc[mt][nt][i] += sw[mt][i] * tmp[i];
            }
        }
    }

    // phase 4: bias via one K=32 MFMA set: acc += what(128x32,bf16) @ bias_t^T(32x64)
    shortx8 wfrag[2];
    #pragma unroll
    for (int mt = 0; mt < 2; mt++)
        wfrag[mt] = *(const shortx8*)&wb[wave * 32 + mt * 16 + m][q * 8];
    #pragma unroll
    for (int nt = 0; nt < 4; nt++) {
        shortx8 btf = *(const shortx8*)(bias_t + (nt * 16 + m) * 32 + q * 8);
        #pragma unroll
        for (int mt = 0; mt < 2; mt++)
            acc[mt][nt] = MFMA_BF16(wfrag[mt], btf, acc[mt][nt]);
    }

    // phase 5: store fp32. D layout: col = m, row = q*4 + i.
    #pragma unroll
    for (int mt = 0; mt < 2; mt++) {
        #pragma unroll
        for (int i = 0; i < 4; i++) {
            int row = wave * 32 + mt * 16 + q * 4 + i;
            int n = nb + row;
            if (n < N) {
                #pragma unroll
                for (int nt = 0; nt < 4; nt++)
                    out[(size_t)n * 64 + nt * 16 + m] = acc[mt][nt][i];
            }
        }
    }
}

extern "C" void kernel_launch(void* const* d_in, const int* in_sizes, int n_in,
                              void* d_out, int out_size, void* d_ws, size_t ws_size,
                              hipStream_t stream) {
    const int*   edge_index = (const int*)d_in[0];     // [2][E] int32
    const int*   edge_type  = (const int*)d_in[1];     // [E]    int32
    const float* emb        = (const float*)d_in[2];   // [N][64]  fp32
    const float* weights    = (const float*)d_in[3];   // [3][18][64][64] fp32
    const float* biases     = (const float*)d_in[4];   // [3][18][64] fp32
    float* out = (float*)d_out;

    const int E = in_sizes[1];
    const int N = in_sizes[2] / 64;

    // workspace layout: [counts int32 N*18][wt bf16 18*64*64][bias_t bf16 64*32]
    int* cnts = (int*)d_ws;
    size_t cnt_bytes = (size_t)N * 18 * sizeof(int);
    ushort* wt     = (ushort*)((char*)d_ws + cnt_bytes);
    ushort* bias_t = wt + 18 * 64 * 64;

    const float* w2 = weights + 2 * 18 * 64 * 64;   // layer 2 only is live
    const float* b2 = biases  + 2 * 18 * 64;

    hipMemsetAsync(d_ws, 0, cnt_bytes, stream);
    {
        int total = 18 * 64 * 64 + 64 * 32;
        rgcn_prep<<<(total + 255) / 256, 256, 0, stream>>>(w2, b2, wt, bias_t);
    }
    rgcn_count<<<(E + 255) / 256, 256, 0, stream>>>(edge_index, edge_type, cnts, E, N);
    rgcn_main<<<(N + 127) / 128, 256, 0, stream>>>(emb, cnts, wt, bias_t, out, N);
}

// Round 3
// 225.339 us; speedup vs baseline: 1.0518x; 1.0518x over previous
//
#include <hip/hip_runtime.h>

// RGCN encoder, MI355X. Algebra (verified, round-2 passed):
//   out[n] = sum_r (c[n][r]/cnt[n]) * (emb[n] @ W2[r] + b2[r]), r in [0,18)
// (only layer-2 weights live; messages scatter to their own source node)
// Round-3 restructure: main kernel was latency-bound (MfmaUtil 7%, VALUBusy
// 10%, 83% stall) on scattered L2 B-fragment loads. Now: prep writes wt in
// MFMA-fragment order; main stages 8KB/r into LDS via global_load_lds w=16
// (coalesced, shared by 4 waves), double-buffered, ds_read_b128 fragments.
// 64 nodes/block -> 1563 blocks for latency hiding.

typedef float  floatx4 __attribute__((ext_vector_type(4)));
typedef short  shortx8 __attribute__((ext_vector_type(8)));

#define MFMA_BF16(A, B, C) __builtin_amdgcn_mfma_f32_16x16x32_bf16((A), (B), (C), 0, 0, 0)

static __device__ __forceinline__ ushort f32_to_bf16_rne(float f) {
    union { float f; unsigned u; } v; v.f = f;
    unsigned r = v.u + 0x7fffu + ((v.u >> 16) & 1u);
    return (ushort)(r >> 16);
}

static __device__ __forceinline__ void gload_lds16(const ushort* g, ushort* l) {
    __builtin_amdgcn_global_load_lds(
        (const __attribute__((address_space(1))) void*)g,
        (__attribute__((address_space(3))) void*)l, 16, 0, 0);
}

// ---- prep: fragment-order swizzle of layer-2 weights + bias
// wt_sw[((r*8 + nt*2+kh)*64 + lane)*8 + j] = bf16(W2[r][k][o]),
//   o = nt*16 + (lane&15), k = kh*32 + (lane>>4)*8 + j
// bias_sw[((nt*64)+lane)*8 + j] = bf16(b2[rr][o]), rr = (lane>>4)*8+j (0 if >=18)
__global__ void rgcn_prep(const float* __restrict__ w2,    // fp32 [18][64][64]
                          const float* __restrict__ b2,    // fp32 [18][64]
                          ushort* __restrict__ wt_sw,      // bf16 [73728]
                          ushort* __restrict__ bias_sw) {  // bf16 [2048]
    int i = blockIdx.x * 256 + threadIdx.x;
    const int WELEMS = 18 * 8 * 64 * 8;   // 73728
    if (i < WELEMS) {
        int r    = i >> 12;
        int rem  = i & 4095;
        int cid  = rem >> 9;          // nt*2+kh
        int lane = (rem >> 3) & 63;
        int j    = i & 7;
        int nt = cid >> 1, kh = cid & 1;
        int o = nt * 16 + (lane & 15);
        int k = kh * 32 + (lane >> 4) * 8 + j;
        wt_sw[i] = f32_to_bf16_rne(w2[(r << 12) + (k << 6) + o]);
    } else {
        int i2 = i - WELEMS;
        if (i2 < 2048) {
            int nt   = i2 >> 9;
            int lane = (i2 >> 3) & 63;
            int j    = i2 & 7;
            int o  = nt * 16 + (lane & 15);
            int rr = (lane >> 4) * 8 + j;
            bias_sw[i2] = (rr < 18) ? f32_to_bf16_rne(b2[rr * 64 + o]) : (ushort)0;
        }
    }
}

// ---- edge incidence counts: c[n][r] for r in [0,18)
__global__ void rgcn_count(const int* __restrict__ ei,  // [2][E] int32
                           const int* __restrict__ et,  // [E]    int32
                           int* __restrict__ cnts,      // [N][18]
                           int E, int N) {
    int e = blockIdx.x * 256 + threadIdx.x;
    if (e < E) {
        int r = et[e];
        int i0 = ei[e];
        int i1 = ei[E + e];
        if ((unsigned)r < 9u) {
            if ((unsigned)i0 < (unsigned)N) atomicAdd(&cnts[i0 * 18 + r], 1);
            if ((unsigned)i1 < (unsigned)N) atomicAdd(&cnts[i1 * 18 + 9 + r], 1);
        }
    }
}

// ---- fused main: 64 nodes/block, 4 waves x (16 rows x 64 cols)
__global__ __launch_bounds__(256) void rgcn_main(
    const float*  __restrict__ emb,      // fp32 [N][64]
    const int*    __restrict__ cnts,     // [N][18]
    const ushort* __restrict__ wt_sw,    // bf16 fragment-order [18][8][64][8]
    const ushort* __restrict__ bias_sw,  // bf16 fragment-order [4][64][8]
    float*        __restrict__ out,      // fp32 [N][64]
    int N)
{
    __shared__ ushort bufB[2][4096];   // double-buffered per-r weight tile (16 KB)
    __shared__ float  wft[18][64];     // w-hat transposed: [r][node]
    __shared__ ushort wb[64][32];      // bf16 w-hat (k-padded) for bias MFMA
    __shared__ int    craw[64 * 18];   // raw counts staging

    const int t    = threadIdx.x;
    const int nb   = blockIdx.x * 64;
    const int wave = t >> 6;
    const int lane = t & 63;
    const int m    = lane & 15;
    const int q    = lane >> 4;

    // coalesced counts load into LDS
    {
        int lim = (N - nb) * 18;
        if (lim > 1152) lim = 1152;
        #pragma unroll
        for (int j = t; j < 1152; j += 256)
            craw[j] = (j < lim) ? cnts[(size_t)nb * 18 + j] : 0;
    }

    // kick staging of r=0 tile (8 KB, coalesced, direct-to-LDS)
    gload_lds16(wt_sw + t * 8,         &bufB[0][t * 8]);
    gload_lds16(wt_sw + (t + 256) * 8, &bufB[0][(t + 256) * 8]);

    // A fragments: row = wave*16 + m, lane holds A[m][k = kh*32 + q*8 + j]
    shortx8 afrag[2];
    {
        int n = nb + wave * 16 + m;
        if (n >= N) n = N - 1;           // contribution zeroed via w-hat=0
        const float* rp = emb + (size_t)n * 64 + q * 8;
        #pragma unroll
        for (int kh = 0; kh < 2; kh++) {
            floatx4 lo = *(const floatx4*)(rp + kh * 32);
            floatx4 hi = *(const floatx4*)(rp + kh * 32 + 4);
            shortx8 f;
            #pragma unroll
            for (int j = 0; j < 4; j++) {
                f[j]     = (short)f32_to_bf16_rne(lo[j]);
                f[j + 4] = (short)f32_to_bf16_rne(hi[j]);
            }
            afrag[kh] = f;
        }
    }

    __syncthreads();   // craw ready

    // per-node normalized relation weights
    if (t < 64) {
        int c[18];
        int cnt = 0;
        #pragma unroll
        for (int r = 0; r < 18; r++) { c[r] = craw[t * 18 + r]; cnt += c[r]; }
        float inv = (cnt > 0) ? (1.0f / (float)cnt) : 0.0f;
        #pragma unroll
        for (int r = 0; r < 18; r++) {
            float w = (float)c[r] * inv;
            wft[r][t] = w;
            wb[t][r] = f32_to_bf16_rne(w);
        }
        #pragma unroll
        for (int r = 18; r < 32; r++) wb[t][r] = 0;
    }

    floatx4 acc[4];
    #pragma unroll
    for (int nt = 0; nt < 4; nt++) acc[nt] = (floatx4){0.f, 0.f, 0.f, 0.f};

    for (int r = 0; r < 18; r++) {
        __syncthreads();   // buf[r&1] staged (vmcnt drain) + phase-1/prev-iter visible
        if (r + 1 < 18) {  // prefetch next tile into other buffer
            const ushort* gp = wt_sw + (r + 1) * 4096;
            ushort* lp = &bufB[(r + 1) & 1][0];
            gload_lds16(gp + t * 8,         lp + t * 8);
            gload_lds16(gp + (t + 256) * 8, lp + (t + 256) * 8);
        }
        const ushort* bb = &bufB[r & 1][0];
        shortx8 bfrag[4][2];
        #pragma unroll
        for (int nt = 0; nt < 4; nt++)
            #pragma unroll
            for (int kh = 0; kh < 2; kh++)
                bfrag[nt][kh] = *(const shortx8*)(bb + ((nt * 2 + kh) * 64 + lane) * 8);

        floatx4 sw = *(const floatx4*)&wft[r][wave * 16 + q * 4];

        #pragma unroll
        for (int nt = 0; nt < 4; nt++) {
            floatx4 tmp = (floatx4){0.f, 0.f, 0.f, 0.f};
            tmp = MFMA_BF16(afrag[0], bfrag[nt][0], tmp);
            tmp = MFMA_BF16(afrag[1], bfrag[nt][1], tmp);
            #pragma unroll
            for (int i = 0; i < 4; i++)
                acc[nt][i] += sw[i] * tmp[i];
        }
    }

    // bias: acc += what(64x32 bf16) @ bias^T(32x64) via one K=32 MFMA per nt
    {
        shortx8 wfrag = *(const shortx8*)&wb[wave * 16 + m][q * 8];
        #pragma unroll
        for (int nt = 0; nt < 4; nt++) {
            shortx8 btf = *(const shortx8*)(bias_sw + ((size_t)nt * 64 + lane) * 8);
            acc[nt] = MFMA_BF16(wfrag, btf, acc[nt]);
        }
    }

    // store fp32; D layout: col = m, row = q*4 + i
    #pragma unroll
    for (int i = 0; i < 4; i++) {
        int nn = nb + wave * 16 + q * 4 + i;
        if (nn < N) {
            #pragma unroll
            for (int nt = 0; nt < 4; nt++)
                out[(size_t)nn * 64 + nt * 16 + m] = acc[nt][i];
        }
    }
}

extern "C" void kernel_launch(void* const* d_in, const int* in_sizes, int n_in,
                              void* d_out, int out_size, void* d_ws, size_t ws_size,
                              hipStream_t stream) {
    const int*   edge_index = (const int*)d_in[0];     // [2][E] int32
    const int*   edge_type  = (const int*)d_in[1];     // [E]    int32
    const float* emb        = (const float*)d_in[2];   // [N][64]  fp32
    const float* weights    = (const float*)d_in[3];   // [3][18][64][64] fp32
    const float* biases     = (const float*)d_in[4];   // [3][18][64] fp32
    float* out = (float*)d_out;

    const int E = in_sizes[1];
    const int N = in_sizes[2] / 64;

    // workspace: [counts int32 N*18][wt_sw bf16 73728][bias_sw bf16 2048]
    int* cnts = (int*)d_ws;
    size_t cnt_bytes = (size_t)N * 18 * sizeof(int);
    ushort* wt_sw   = (ushort*)((char*)d_ws + cnt_bytes);
    ushort* bias_sw = wt_sw + 18 * 8 * 64 * 8;

    const float* w2 = weights + 2 * 18 * 64 * 64;   // only layer 2 is live
    const float* b2 = biases  + 2 * 18 * 64;

    hipMemsetAsync(d_ws, 0, cnt_bytes, stream);
    {
        int total = 18 * 8 * 64 * 8 + 2048;          // 75776
        rgcn_prep<<<(total + 255) / 256, 256, 0, stream>>>(w2, b2, wt_sw, bias_sw);
    }
    rgcn_count<<<(E + 255) / 256, 256, 0, stream>>>(edge_index, edge_type, cnts, E, N);
    rgcn_main<<<(N + 63) / 64, 256, 0, stream>>>(emb, cnts, wt_sw, bias_sw, out, N);
}

// Round 4
// 190.748 us; speedup vs baseline: 1.2425x; 1.1813x over previous
//
#include <hip/hip_runtime.h>

// RGCN encoder, MI355X.  out[n] = sum_r (c[n][r]/cnt[n]) * (emb[n]@W2[r] + b2[r])
// (only layer-2 weights live; messages scatter to their own source node).
// Round-4: rounds 2/3 both ~80us with ALL pipes idle (Mfma 7%, VALU 9%, HBM 6%)
// regardless of weight-delivery scheme => latency-bound lockstep on barrier-
// gated r-loop. This version: NO barriers in the r-loop. B-fragments stream
// global->register fully coalesced (1KB/load, L1-shared across waves),
// 2-deep software pipeline; 128 nodes/block, 782 blocks = 3/CU all-resident.

typedef float  floatx4 __attribute__((ext_vector_type(4)));
typedef short  shortx8 __attribute__((ext_vector_type(8)));

#define MFMA_BF16(A, B, C) __builtin_amdgcn_mfma_f32_16x16x32_bf16((A), (B), (C), 0, 0, 0)

static __device__ __forceinline__ ushort f32_to_bf16_rne(float f) {
    union { float f; unsigned u; } v; v.f = f;
    unsigned r = v.u + 0x7fffu + ((v.u >> 16) & 1u);
    return (ushort)(r >> 16);
}

// ---- prep: fragment-order swizzle of layer-2 weights + bias (unchanged r3)
// wt_sw[((r*8 + nt*2+kh)*64 + lane)*8 + j] = bf16(W2[r][k][o]),
//   o = nt*16 + (lane&15), k = kh*32 + (lane>>4)*8 + j
__global__ void rgcn_prep(const float* __restrict__ w2,    // fp32 [18][64][64]
                          const float* __restrict__ b2,    // fp32 [18][64]
                          ushort* __restrict__ wt_sw,      // bf16 [73728]
                          ushort* __restrict__ bias_sw) {  // bf16 [2048]
    int i = blockIdx.x * 256 + threadIdx.x;
    const int WELEMS = 18 * 8 * 64 * 8;   // 73728
    if (i < WELEMS) {
        int r    = i >> 12;
        int rem  = i & 4095;
        int cid  = rem >> 9;          // nt*2+kh
        int lane = (rem >> 3) & 63;
        int j    = i & 7;
        int nt = cid >> 1, kh = cid & 1;
        int o = nt * 16 + (lane & 15);
        int k = kh * 32 + (lane >> 4) * 8 + j;
        wt_sw[i] = f32_to_bf16_rne(w2[(r << 12) + (k << 6) + o]);
    } else {
        int i2 = i - WELEMS;
        if (i2 < 2048) {
            int nt   = i2 >> 9;
            int lane = (i2 >> 3) & 63;
            int j    = i2 & 7;
            int o  = nt * 16 + (lane & 15);
            int rr = (lane >> 4) * 8 + j;
            bias_sw[i2] = (rr < 18) ? f32_to_bf16_rne(b2[rr * 64 + o]) : (ushort)0;
        }
    }
}

// ---- edge incidence counts: c[n][r] for r in [0,18)
__global__ void rgcn_count(const int* __restrict__ ei,  // [2][E] int32
                           const int* __restrict__ et,  // [E]    int32
                           int* __restrict__ cnts,      // [N][18]
                           int E, int N) {
    int e = blockIdx.x * 256 + threadIdx.x;
    if (e < E) {
        int r = et[e];
        int i0 = ei[e];
        int i1 = ei[E + e];
        if ((unsigned)r < 9u) {
            if ((unsigned)i0 < (unsigned)N) atomicAdd(&cnts[i0 * 18 + r], 1);
            if ((unsigned)i1 < (unsigned)N) atomicAdd(&cnts[i1 * 18 + 9 + r], 1);
        }
    }
}

// ---- main: 128 nodes/block, 4 waves x (2 m-tiles x 4 n-tiles), barrier-free r-loop
__global__ __launch_bounds__(256, 3) void rgcn_main(
    const float*  __restrict__ emb,      // fp32 [N][64]
    const int*    __restrict__ cnts,     // [N][18]
    const ushort* __restrict__ wt_sw,    // bf16 fragment-order [18][8][64][8]
    const ushort* __restrict__ bias_sw,  // bf16 fragment-order [4][64][8]
    float*        __restrict__ out,      // fp32 [N][64]
    int N)
{
    __shared__ float  wft[18][128];   // w-hat transposed [r][node]   9216 B
    __shared__ ushort wb[128][32];    // bf16 w-hat (k-padded)        8192 B
    __shared__ int    craw[128 * 18]; // counts staging               9216 B

    const int t    = threadIdx.x;
    const int nb   = blockIdx.x * 128;
    const int wave = t >> 6;
    const int lane = t & 63;
    const int m    = lane & 15;
    const int q    = lane >> 4;

    // stage counts, coalesced
    {
        int lim = (N - nb) * 18;
        if (lim > 2304) lim = 2304;
        #pragma unroll
        for (int j = t; j < 2304; j += 256)
            craw[j] = (j < lim) ? cnts[(size_t)nb * 18 + j] : 0;
    }

    // A fragments: row = wave*32 + mt*16 + m; lane holds A[m][kh*32 + q*8 + j]
    shortx8 af[2][2];
    #pragma unroll
    for (int mt = 0; mt < 2; mt++) {
        int n = nb + wave * 32 + mt * 16 + m;
        if (n >= N) n = N - 1;          // contribution zeroed via w-hat=0
        const float* rp = emb + (size_t)n * 64 + q * 8;
        #pragma unroll
        for (int kh = 0; kh < 2; kh++) {
            floatx4 lo = *(const floatx4*)(rp + kh * 32);
            floatx4 hi = *(const floatx4*)(rp + kh * 32 + 4);
            shortx8 f;
            #pragma unroll
            for (int j = 0; j < 4; j++) {
                f[j]     = (short)f32_to_bf16_rne(lo[j]);
                f[j + 4] = (short)f32_to_bf16_rne(hi[j]);
            }
            af[mt][kh] = f;
        }
    }

    // prefetch B fragments for r=0 (independent of LDS phases)
    const ushort* wbase = wt_sw + (size_t)lane * 8;
    shortx8 bfA[8], bfB[8];
    #pragma unroll
    for (int c = 0; c < 8; c++) bfA[c] = *(const shortx8*)(wbase + c * 512);

    __syncthreads();   // craw ready

    // per-node normalized relation weights (waves 0-1)
    if (t < 128) {
        int c[18];
        int cnt = 0;
        #pragma unroll
        for (int r = 0; r < 18; r++) { c[r] = craw[t * 18 + r]; cnt += c[r]; }
        float inv = (cnt > 0) ? (1.0f / (float)cnt) : 0.0f;
        #pragma unroll
        for (int r = 0; r < 18; r++) {
            float w = (float)c[r] * inv;
            wft[r][t] = w;
            wb[t][r] = f32_to_bf16_rne(w);
        }
        #pragma unroll
        for (int r = 18; r < 32; r++) wb[t][r] = 0;
    }

    __syncthreads();   // wft/wb ready — last barrier in the kernel

    floatx4 acc[2][4];
    #pragma unroll
    for (int mt = 0; mt < 2; mt++)
        #pragma unroll
        for (int nt = 0; nt < 4; nt++)
            acc[mt][nt] = (floatx4){0.f, 0.f, 0.f, 0.f};

    // r-loop: 2-deep software pipeline, zero barriers
    for (int r = 0; r < 18; r += 2) {
        {   // prefetch r+1 into bfB
            const ushort* p = wbase + (r + 1) * 4096;
            #pragma unroll
            for (int c = 0; c < 8; c++) bfB[c] = *(const shortx8*)(p + c * 512);
        }
        {   // compute r with bfA
            floatx4 swv[2];
            #pragma unroll
            for (int mt = 0; mt < 2; mt++)
                swv[mt] = *(const floatx4*)&wft[r][wave * 32 + mt * 16 + q * 4];
            #pragma unroll
            for (int nt = 0; nt < 4; nt++)
                #pragma unroll
                for (int mt = 0; mt < 2; mt++) {
                    floatx4 tmp = (floatx4){0.f, 0.f, 0.f, 0.f};
                    tmp = MFMA_BF16(af[mt][0], bfA[nt * 2 + 0], tmp);
                    tmp = MFMA_BF16(af[mt][1], bfA[nt * 2 + 1], tmp);
                    acc[mt][nt] += swv[mt] * tmp;
                }
        }
        if (r + 2 < 18) {   // prefetch r+2 into bfA
            const ushort* p = wbase + (r + 2) * 4096;
            #pragma unroll
            for (int c = 0; c < 8; c++) bfA[c] = *(const shortx8*)(p + c * 512);
        }
        {   // compute r+1 with bfB
            floatx4 swv[2];
            #pragma unroll
            for (int mt = 0; mt < 2; mt++)
                swv[mt] = *(const floatx4*)&wft[r + 1][wave * 32 + mt * 16 + q * 4];
            #pragma unroll
            for (int nt = 0; nt < 4; nt++)
                #pragma unroll
                for (int mt = 0; mt < 2; mt++) {
                    floatx4 tmp = (floatx4){0.f, 0.f, 0.f, 0.f};
                    tmp = MFMA_BF16(af[mt][0], bfB[nt * 2 + 0], tmp);
                    tmp = MFMA_BF16(af[mt][1], bfB[nt * 2 + 1], tmp);
                    acc[mt][nt] += swv[mt] * tmp;
                }
        }
    }

    // bias: acc += what(bf16) @ bias^T via one K=32 MFMA per (mt,nt)
    {
        shortx8 wfrag[2];
        #pragma unroll
        for (int mt = 0; mt < 2; mt++)
            wfrag[mt] = *(const shortx8*)&wb[wave * 32 + mt * 16 + m][q * 8];
        #pragma unroll
        for (int nt = 0; nt < 4; nt++) {
            shortx8 btf = *(const shortx8*)(bias_sw + ((size_t)nt * 64 + lane) * 8);
            #pragma unroll
            for (int mt = 0; mt < 2; mt++)
                acc[mt][nt] = MFMA_BF16(wfrag[mt], btf, acc[mt][nt]);
        }
    }

    // store fp32; D layout: col = nt*16 + m, row = q*4 + i
    #pragma unroll
    for (int mt = 0; mt < 2; mt++)
        #pragma unroll
        for (int i = 0; i < 4; i++) {
            int nn = nb + wave * 32 + mt * 16 + q * 4 + i;
            if (nn < N) {
                #pragma unroll
                for (int nt = 0; nt < 4; nt++)
                    out[(size_t)nn * 64 + nt * 16 + m] = acc[mt][nt][i];
            }
        }
}

extern "C" void kernel_launch(void* const* d_in, const int* in_sizes, int n_in,
                              void* d_out, int out_size, void* d_ws, size_t ws_size,
                              hipStream_t stream) {
    const int*   edge_index = (const int*)d_in[0];     // [2][E] int32
    const int*   edge_type  = (const int*)d_in[1];     // [E]    int32
    const float* emb        = (const float*)d_in[2];   // [N][64]  fp32
    const float* weights    = (const float*)d_in[3];   // [3][18][64][64] fp32
    const float* biases     = (const float*)d_in[4];   // [3][18][64] fp32
    float* out = (float*)d_out;

    const int E = in_sizes[1];
    const int N = in_sizes[2] / 64;

    // workspace: [counts int32 N*18][wt_sw bf16 73728][bias_sw bf16 2048]
    int* cnts = (int*)d_ws;
    size_t cnt_bytes = (size_t)N * 18 * sizeof(int);
    ushort* wt_sw   = (ushort*)((char*)d_ws + cnt_bytes);
    ushort* bias_sw = wt_sw + 18 * 8 * 64 * 8;

    const float* w2 = weights + 2 * 18 * 64 * 64;   // only layer 2 is live
    const float* b2 = biases  + 2 * 18 * 64;

    hipMemsetAsync(d_ws, 0, cnt_bytes, stream);
    {
        int total = 18 * 8 * 64 * 8 + 2048;          // 75776
        rgcn_prep<<<(total + 255) / 256, 256, 0, stream>>>(w2, b2, wt_sw, bias_sw);
    }
    rgcn_count<<<(E + 255) / 256, 256, 0, stream>>>(edge_index, edge_type, cnts, E, N);
    rgcn_main<<<(N + 127) / 128, 256, 0, stream>>>(emb, cnts, wt_sw, bias_sw, out, N);
}

// Round 5
// 150.906 us; speedup vs baseline: 1.5705x; 1.2640x over previous
//
#include <hip/hip_runtime.h>

// RGCN encoder, MI355X.  out[n] = sum_r (c[n][r]/cnt[n]) * (emb[n]@W2[r] + b2[r])
// (only layer-2 weights live; messages scatter to their own source node).
// Round-5: rgcn_count was the bottleneck (79.6us, VALU 0.6%, 62.5MB WRITE =
// 2M scattered atomics x 32B fabric transactions => device scatter-atomic
// op-rate ceiling ~25G/s). Replaced with binned counting: LDS histogram ->
// per-(block,bucket) reservation -> u16 key scatter -> per-bucket LDS count.
// Zero scattered global atomics. Main kernel unchanged from round 4.

typedef float  floatx4 __attribute__((ext_vector_type(4)));
typedef short  shortx8 __attribute__((ext_vector_type(8)));

#define MFMA_BF16(A, B, C) __builtin_amdgcn_mfma_f32_16x16x32_bf16((A), (B), (C), 0, 0, 0)

#define SCAT_GRID 512
#define BKT_CAP   6144     // expected load 2M/440=4545, std ~67 -> >20 sigma

static __device__ __forceinline__ ushort f32_to_bf16_rne(float f) {
    union { float f; unsigned u; } v; v.f = f;
    unsigned r = v.u + 0x7fffu + ((v.u >> 16) & 1u);
    return (ushort)(r >> 16);
}

// ---- prep: fragment-order swizzle of layer-2 weights + bias
// wt_sw[((r*8 + nt*2+kh)*64 + lane)*8 + j] = bf16(W2[r][k][o]),
//   o = nt*16 + (lane&15), k = kh*32 + (lane>>4)*8 + j
__global__ void rgcn_prep(const float* __restrict__ w2,    // fp32 [18][64][64]
                          const float* __restrict__ b2,    // fp32 [18][64]
                          ushort* __restrict__ wt_sw,      // bf16 [73728]
                          ushort* __restrict__ bias_sw) {  // bf16 [2048]
    int i = blockIdx.x * 256 + threadIdx.x;
    const int WELEMS = 18 * 8 * 64 * 8;   // 73728
    if (i < WELEMS) {
        int r    = i >> 12;
        int rem  = i & 4095;
        int cid  = rem >> 9;          // nt*2+kh
        int lane = (rem >> 3) & 63;
        int j    = i & 7;
        int nt = cid >> 1, kh = cid & 1;
        int o = nt * 16 + (lane & 15);
        int k = kh * 32 + (lane >> 4) * 8 + j;
        wt_sw[i] = f32_to_bf16_rne(w2[(r << 12) + (k << 6) + o]);
    } else {
        int i2 = i - WELEMS;
        if (i2 < 2048) {
            int nt   = i2 >> 9;
            int lane = (i2 >> 3) & 63;
            int j    = i2 & 7;
            int o  = nt * 16 + (lane & 15);
            int rr = (lane >> 4) * 8 + j;
            bias_sw[i2] = (rr < 18) ? f32_to_bf16_rne(b2[rr * 64 + o]) : (ushort)0;
        }
    }
}

// ---- fallback counting (scattered atomics) if ws too small
__global__ void rgcn_count(const int* __restrict__ ei, const int* __restrict__ et,
                           int* __restrict__ cnts, int E, int N) {
    int e = blockIdx.x * 256 + threadIdx.x;
    if (e < E) {
        int r = et[e];
        int i0 = ei[e];
        int i1 = ei[E + e];
        if ((unsigned)r < 9u) {
            if ((unsigned)i0 < (unsigned)N) atomicAdd(&cnts[i0 * 18 + r], 1);
            if ((unsigned)i1 < (unsigned)N) atomicAdd(&cnts[i1 * 18 + 9 + r], 1);
        }
    }
}

// ---- pass A: bin keys k=n*18+r into 4096-key buckets (bucket = k>>12)
__global__ __launch_bounds__(256) void rgcn_scatter(
    const int* __restrict__ ei,      // [2][E]
    const int* __restrict__ et,      // [E]
    unsigned*  __restrict__ cursors, // [512] zeroed
    ushort*    __restrict__ bkt,     // [512][BKT_CAP] low-12-bits of keys
    int E, int N)
{
    __shared__ unsigned hist[512];
    const int t = threadIdx.x;
    #pragma unroll
    for (int b = t; b < 512; b += 256) hist[b] = 0;
    __syncthreads();

    const int epb = (E + SCAT_GRID - 1) / SCAT_GRID;
    const int e0 = blockIdx.x * epb;
    const int e1 = (e0 + epb < E) ? e0 + epb : E;
    const unsigned KMAX = (unsigned)N * 18u;

    // phase 1: block-local histogram over buckets (LDS atomics)
    for (int e = e0 + t; e < e1; e += 256) {
        int r = et[e]; int i0 = ei[e]; int i1 = ei[E + e];
        if ((unsigned)r < 9u) {
            unsigned k0 = (unsigned)i0 * 18u + (unsigned)r;
            unsigned k1 = (unsigned)i1 * 18u + 9u + (unsigned)r;
            if (k0 < KMAX) atomicAdd(&hist[k0 >> 12], 1u);
            if (k1 < KMAX) atomicAdd(&hist[k1 >> 12], 1u);
        }
    }
    __syncthreads();

    // phase 2: one global reservation per (block,bucket); hist becomes abs cursor
    for (int b = t; b < 512; b += 256) {
        unsigned c = hist[b];
        hist[b] = c ? atomicAdd(&cursors[b], c) : 0u;
    }
    __syncthreads();

    // phase 3: scatter key remainders to reserved slots (LDS atomics for offsets)
    for (int e = e0 + t; e < e1; e += 256) {
        int r = et[e]; int i0 = ei[e]; int i1 = ei[E + e];
        if ((unsigned)r < 9u) {
            unsigned k0 = (unsigned)i0 * 18u + (unsigned)r;
            unsigned k1 = (unsigned)i1 * 18u + 9u + (unsigned)r;
            if (k0 < KMAX) {
                unsigned o = atomicAdd(&hist[k0 >> 12], 1u);
                if (o < BKT_CAP) bkt[(size_t)(k0 >> 12) * BKT_CAP + o] = (ushort)(k0 & 4095u);
            }
            if (k1 < KMAX) {
                unsigned o = atomicAdd(&hist[k1 >> 12], 1u);
                if (o < BKT_CAP) bkt[(size_t)(k1 >> 12) * BKT_CAP + o] = (ushort)(k1 & 4095u);
            }
        }
    }
}

// ---- pass B: per-bucket LDS histogram -> coalesced cnts write (covers all of cnts)
__global__ __launch_bounds__(256) void rgcn_bucket_count(
    const ushort*   __restrict__ bkt,
    const unsigned* __restrict__ cursors,
    int*            __restrict__ cnts,   // [N*18]
    int N)
{
    __shared__ int cnt[4096];   // 16 KB
    const int t = threadIdx.x;
    const int b = blockIdx.x;
    #pragma unroll
    for (int i = t; i < 4096; i += 256) cnt[i] = 0;
    __syncthreads();

    unsigned n = cursors[b];
    if (n > BKT_CAP) n = BKT_CAP;
    const ushort* bp = bkt + (size_t)b * BKT_CAP;
    for (unsigned i = t; i < n; i += 256)
        atomicAdd(&cnt[bp[i]], 1);
    __syncthreads();

    const int base = b << 12;
    const int lim = N * 18;
    #pragma unroll
    for (int i = t; i < 4096; i += 256)
        if (base + i < lim) cnts[base + i] = cnt[i];
}

// ---- main: 128 nodes/block, 4 waves x (2 m-tiles x 4 n-tiles), barrier-free r-loop
__global__ __launch_bounds__(256, 3) void rgcn_main(
    const float*  __restrict__ emb,      // fp32 [N][64]
    const int*    __restrict__ cnts,     // [N][18]
    const ushort* __restrict__ wt_sw,    // bf16 fragment-order [18][8][64][8]
    const ushort* __restrict__ bias_sw,  // bf16 fragment-order [4][64][8]
    float*        __restrict__ out,      // fp32 [N][64]
    int N)
{
    __shared__ float  wft[18][128];
    __shared__ ushort wb[128][32];
    __shared__ int    craw[128 * 18];

    const int t    = threadIdx.x;
    const int nb   = blockIdx.x * 128;
    const int wave = t >> 6;
    const int lane = t & 63;
    const int m    = lane & 15;
    const int q    = lane >> 4;

    {
        int lim = (N - nb) * 18;
        if (lim > 2304) lim = 2304;
        #pragma unroll
        for (int j = t; j < 2304; j += 256)
            craw[j] = (j < lim) ? cnts[(size_t)nb * 18 + j] : 0;
    }

    shortx8 af[2][2];
    #pragma unroll
    for (int mt = 0; mt < 2; mt++) {
        int n = nb + wave * 32 + mt * 16 + m;
        if (n >= N) n = N - 1;          // contribution zeroed via w-hat=0
        const float* rp = emb + (size_t)n * 64 + q * 8;
        #pragma unroll
        for (int kh = 0; kh < 2; kh++) {
            floatx4 lo = *(const floatx4*)(rp + kh * 32);
            floatx4 hi = *(const floatx4*)(rp + kh * 32 + 4);
            shortx8 f;
            #pragma unroll
            for (int j = 0; j < 4; j++) {
                f[j]     = (short)f32_to_bf16_rne(lo[j]);
                f[j + 4] = (short)f32_to_bf16_rne(hi[j]);
            }
            af[mt][kh] = f;
        }
    }

    const ushort* wbase = wt_sw + (size_t)lane * 8;
    shortx8 bfA[8], bfB[8];
    #pragma unroll
    for (int c = 0; c < 8; c++) bfA[c] = *(const shortx8*)(wbase + c * 512);

    __syncthreads();   // craw ready

    if (t < 128) {
        int c[18];
        int cnt = 0;
        #pragma unroll
        for (int r = 0; r < 18; r++) { c[r] = craw[t * 18 + r]; cnt += c[r]; }
        float inv = (cnt > 0) ? (1.0f / (float)cnt) : 0.0f;
        #pragma unroll
        for (int r = 0; r < 18; r++) {
            float w = (float)c[r] * inv;
            wft[r][t] = w;
            wb[t][r] = f32_to_bf16_rne(w);
        }
        #pragma unroll
        for (int r = 18; r < 32; r++) wb[t][r] = 0;
    }

    __syncthreads();   // wft/wb ready — last barrier

    floatx4 acc[2][4];
    #pragma unroll
    for (int mt = 0; mt < 2; mt++)
        #pragma unroll
        for (int nt = 0; nt < 4; nt++)
            acc[mt][nt] = (floatx4){0.f, 0.f, 0.f, 0.f};

    for (int r = 0; r < 18; r += 2) {
        {
            const ushort* p = wbase + (r + 1) * 4096;
            #pragma unroll
            for (int c = 0; c < 8; c++) bfB[c] = *(const shortx8*)(p + c * 512);
        }
        {
            floatx4 swv[2];
            #pragma unroll
            for (int mt = 0; mt < 2; mt++)
                swv[mt] = *(const floatx4*)&wft[r][wave * 32 + mt * 16 + q * 4];
            #pragma unroll
            for (int nt = 0; nt < 4; nt++)
                #pragma unroll
                for (int mt = 0; mt < 2; mt++) {
                    floatx4 tmp = (floatx4){0.f, 0.f, 0.f, 0.f};
                    tmp = MFMA_BF16(af[mt][0], bfA[nt * 2 + 0], tmp);
                    tmp = MFMA_BF16(af[mt][1], bfA[nt * 2 + 1], tmp);
                    acc[mt][nt] += swv[mt] * tmp;
                }
        }
        if (r + 2 < 18) {
            const ushort* p = wbase + (r + 2) * 4096;
            #pragma unroll
            for (int c = 0; c < 8; c++) bfA[c] = *(const shortx8*)(p + c * 512);
        }
        {
            floatx4 swv[2];
            #pragma unroll
            for (int mt = 0; mt < 2; mt++)
                swv[mt] = *(const floatx4*)&wft[r + 1][wave * 32 + mt * 16 + q * 4];
            #pragma unroll
            for (int nt = 0; nt < 4; nt++)
                #pragma unroll
                for (int mt = 0; mt < 2; mt++) {
                    floatx4 tmp = (floatx4){0.f, 0.f, 0.f, 0.f};
                    tmp = MFMA_BF16(af[mt][0], bfB[nt * 2 + 0], tmp);
                    tmp = MFMA_BF16(af[mt][1], bfB[nt * 2 + 1], tmp);
                    acc[mt][nt] += swv[mt] * tmp;
                }
        }
    }

    {
        shortx8 wfrag[2];
        #pragma unroll
        for (int mt = 0; mt < 2; mt++)
            wfrag[mt] = *(const shortx8*)&wb[wave * 32 + mt * 16 + m][q * 8];
        #pragma unroll
        for (int nt = 0; nt < 4; nt++) {
            shortx8 btf = *(const shortx8*)(bias_sw + ((size_t)nt * 64 + lane) * 8);
            #pragma unroll
            for (int mt = 0; mt < 2; mt++)
                acc[mt][nt] = MFMA_BF16(wfrag[mt], btf, acc[mt][nt]);
        }
    }

    #pragma unroll
    for (int mt = 0; mt < 2; mt++)
        #pragma unroll
        for (int i = 0; i < 4; i++) {
            int nn = nb + wave * 32 + mt * 16 + q * 4 + i;
            if (nn < N) {
                #pragma unroll
                for (int nt = 0; nt < 4; nt++)
                    out[(size_t)nn * 64 + nt * 16 + m] = acc[mt][nt][i];
            }
        }
}

extern "C" void kernel_launch(void* const* d_in, const int* in_sizes, int n_in,
                              void* d_out, int out_size, void* d_ws, size_t ws_size,
                              hipStream_t stream) {
    const int*   edge_index = (const int*)d_in[0];     // [2][E] int32
    const int*   edge_type  = (const int*)d_in[1];     // [E]    int32
    const float* emb        = (const float*)d_in[2];   // [N][64]  fp32
    const float* weights    = (const float*)d_in[3];   // [3][18][64][64] fp32
    const float* biases     = (const float*)d_in[4];   // [3][18][64] fp32
    float* out = (float*)d_out;

    const int E = in_sizes[1];
    const int N = in_sizes[2] / 64;

    const float* w2 = weights + 2 * 18 * 64 * 64;   // only layer 2 is live
    const float* b2 = biases  + 2 * 18 * 64;

    // ws layout (64B-aligned chunks):
    //   [cursors u32*512][cnts i32*N*18][bkt u16*512*CAP][wt_sw bf16][bias_sw bf16]
    size_t off = 0;
    unsigned* cursors = (unsigned*)((char*)d_ws + off);  off += 512 * 4;
    off = (off + 63) & ~size_t(63);
    int* cnts = (int*)((char*)d_ws + off);               off += (size_t)N * 18 * 4;
    off = (off + 63) & ~size_t(63);
    ushort* bkt = (ushort*)((char*)d_ws + off);          off += (size_t)512 * BKT_CAP * 2;
    off = (off + 63) & ~size_t(63);
    ushort* wt_sw = (ushort*)((char*)d_ws + off);        off += 73728 * 2;
    off = (off + 63) & ~size_t(63);
    ushort* bias_sw = (ushort*)((char*)d_ws + off);      off += 2048 * 2;
    size_t need = off;

    int nbuckets = (N * 18 + 4095) >> 12;

    {
        int total = 18 * 8 * 64 * 8 + 2048;          // 75776
        rgcn_prep<<<(total + 255) / 256, 256, 0, stream>>>(w2, b2, wt_sw, bias_sw);
    }

    if (ws_size >= need && nbuckets <= 512) {
        // binned counting: no scattered global atomics
        hipMemsetAsync(cursors, 0, 512 * 4, stream);
        rgcn_scatter<<<SCAT_GRID, 256, 0, stream>>>(edge_index, edge_type, cursors, bkt, E, N);
        rgcn_bucket_count<<<nbuckets, 256, 0, stream>>>(bkt, cursors, cnts, N);
    } else {
        // fallback: scattered atomics (round-4 path); reuse cnts right after cursors
        cnts = (int*)((char*)d_ws + 64);
        wt_sw = (ushort*)((char*)cnts + (size_t)N * 18 * 4);
        bias_sw = wt_sw + 73728;
        rgcn_prep<<<(18 * 8 * 64 * 8 + 2048 + 255) / 256, 256, 0, stream>>>(w2, b2, wt_sw, bias_sw);
        hipMemsetAsync(cnts, 0, (size_t)N * 18 * 4, stream);
        rgcn_count<<<(E + 255) / 256, 256, 0, stream>>>(edge_index, edge_type, cnts, E, N);
    }

    rgcn_main<<<(N + 127) / 128, 256, 0, stream>>>(emb, cnts, wt_sw, bias_sw, out, N);
}